// Round 18
// baseline (247.575 us; speedup 1.0000x reference)
//
#include <hip/hip_runtime.h>

#define NB    4096
#define SEQ   64
#define DIM   128
#define NHEAD 8
#define ATTD  32
#define HKC   256
#define SCALE 0.17677669529663687f
#define LOG2E 1.4426950408889634f

typedef __bf16 bf16_t;
typedef __bf16 bf16x8 __attribute__((ext_vector_type(8)));
typedef __bf16 bf16x4 __attribute__((ext_vector_type(4)));
typedef float  f32x4  __attribute__((ext_vector_type(4)));
typedef short  s16x4  __attribute__((ext_vector_type(4)));
typedef unsigned int u32;

// K=16 MFMA: A/B frag layout (row/col=lane&15, k=4*(lane>>4)+elem) == the
// D-layout of a 16x16 MFMA (col=lane&15, row=4*(lane>>4)+reg). Any 16x16
// D-tile feeds the next MFMA's K-dim directly after an in-lane f32->bf16 pack.
#define MFMA16(a, b, c) __builtin_amdgcn_mfma_f32_16x16x16bf16_1k(a, b, c, 0, 0, 0)

// native casts -> v_cvt_pk_bf16_f32 (RNE)
static __device__ __forceinline__ u32 pkbf(float a, float b) {
  unsigned short ua = __builtin_bit_cast(unsigned short, (__bf16)a);
  unsigned short ub = __builtin_bit_cast(unsigned short, (__bf16)b);
  return (u32)ua | ((u32)ub << 16);
}

// pack a 16x16 D-tile (4 f32 regs) into a K=16 A/B frag (4 bf16 = 2 regs),
// pure in-lane: elem e = reg j. No shuffles, no LDS.
static __device__ __forceinline__ s16x4 pk4(f32x4 t) {
  union { u32 u[2]; s16x4 s; } r;
  r.u[0] = pkbf(t[0], t[1]);
  r.u[1] = pkbf(t[2], t[3]);
  return r.s;
}

// XOR swizzle on element index (XOR bits >=3 only: 16B blocks stay contiguous)
#define XSWZ(r, c) (((r) << 7) + ((c) ^ (((r) & 7) << 3)))   // Xb: 64x128

// ws layout (bf16): [0:32768) WqT[c][d] (pre-scaled by SCALE*log2e),
// [32768:65536) WkT, [65536:98304) WvT, [98304:131072) WresT.
__global__ void prep_weights(const float* __restrict__ Wq,
                             const float* __restrict__ Wk,
                             const float* __restrict__ Wv,
                             const float* __restrict__ Wr,
                             bf16_t* __restrict__ ws) {
  int idx = blockIdx.x * 256 + threadIdx.x;  // 0..131071
  int m = idx >> 15;
  int e = idx & 32767;
  int c = e >> 7;
  int d = e & 127;
  float v;
  if (m == 0)      v = Wq[((c >> 5) * DIM + d) * ATTD + (c & 31)] * (SCALE * LOG2E);
  else if (m == 1) v = Wk[((c >> 5) * DIM + d) * ATTD + (c & 31)];
  else if (m == 2) v = Wv[((c >> 5) * DIM + d) * ATTD + (c & 31)];
  else             v = Wr[d * HKC + c];
  ws[idx] = (bf16_t)v;
}

// R17's K=16 in-register structure, re-budgeted for 4 waves/SIMD:
// per-mt narrow output (ch[2] = 8 regs; res + PV + store inside the mt
// iteration). Peak live state ~100 unified regs -> fits the 128/wave that
// __launch_bounds__(256,4) grants. No LDS for V/P; Xb (16 KB) only.
__launch_bounds__(256, 4)
__global__ void fused_attn(const float* __restrict__ xg,
                           const bf16_t* __restrict__ ws,
                           float* __restrict__ outg) {
  __shared__ bf16_t Xb[64 * 128];   // only LDS (16 KB)

  const int t  = threadIdx.x;
  const int w  = t >> 6;
  const int l  = t & 63;
  const int lo = l & 15;
  const int g  = l >> 4;
  const int b  = blockIdx.x;

  { // stage X -> LDS (bf16, swizzled)
    const float* xb = xg + (size_t)b * (SEQ * DIM);
#pragma unroll
    for (int i = 0; i < 8; ++i) {
      int idx = i * 1024 + t * 4;
      float4 v = *(const float4*)(xb + idx);
      bf16x4 p;
      p[0] = (bf16_t)v.x; p[1] = (bf16_t)v.y; p[2] = (bf16_t)v.z; p[3] = (bf16_t)v.w;
      *(bf16x4*)&Xb[XSWZ(idx >> 7, idx & 127)] = p;
    }
  }
  __syncthreads();

  const bf16_t* wsq = ws;
  const bf16_t* wsk = ws + 32768;
  const bf16_t* wsv = ws + 65536;
  const bf16_t* wsr = ws + 98304;
  float* ob = outg + (size_t)b * (SEQ * HKC);
  const f32x4 z4 = {0.f, 0.f, 0.f, 0.f};

#pragma unroll
  for (int hh = 0; hh < 2; ++hh) {
    const int hc = w * 64 + hh * 32;  // weight col base == output col base

    s16x4 kfr[2][4], vfr[4][2], qfr[2][4];

    { // ---- K^T = Wk^T X^T : tiles [at][nt] (rows a, cols n) -> kfr ----
      f32x4 acck[2][4];
#pragma unroll
      for (int i = 0; i < 2; ++i)
#pragma unroll
        for (int j = 0; j < 4; ++j) acck[i][j] = z4;
#pragma unroll
      for (int kk = 0; kk < 4; ++kk) {
        bf16x8 aw[2], bx[4];
#pragma unroll
        for (int at = 0; at < 2; ++at)
          aw[at] = *(const bf16x8*)(wsk + (hc + at * 16 + lo) * DIM + kk * 32 + g * 8);
#pragma unroll
        for (int nt = 0; nt < 4; ++nt)
          bx[nt] = *(const bf16x8*)&Xb[XSWZ(nt * 16 + lo, kk * 32 + g * 8)];
        __builtin_amdgcn_s_setprio(1);
#pragma unroll
        for (int at = 0; at < 2; ++at)
#pragma unroll
          for (int nt = 0; nt < 4; ++nt)
            acck[at][nt] = __builtin_amdgcn_mfma_f32_16x16x32_bf16(aw[at], bx[nt], acck[at][nt], 0, 0, 0);
        __builtin_amdgcn_s_setprio(0);
      }
#pragma unroll
      for (int at = 0; at < 2; ++at)
#pragma unroll
        for (int nt = 0; nt < 4; ++nt) kfr[at][nt] = pk4(acck[at][nt]);
    }

    { // ---- V = X Wv : tiles [nt][ct] (rows n, cols c) -> vfr ----
      f32x4 accv[4][2];
#pragma unroll
      for (int i = 0; i < 4; ++i)
#pragma unroll
        for (int j = 0; j < 2; ++j) accv[i][j] = z4;
#pragma unroll
      for (int kk = 0; kk < 4; ++kk) {
        bf16x8 ax[4], bw[2];
#pragma unroll
        for (int nt = 0; nt < 4; ++nt)
          ax[nt] = *(const bf16x8*)&Xb[XSWZ(nt * 16 + lo, kk * 32 + g * 8)];
#pragma unroll
        for (int ct = 0; ct < 2; ++ct)
          bw[ct] = *(const bf16x8*)(wsv + (hc + ct * 16 + lo) * DIM + kk * 32 + g * 8);
        __builtin_amdgcn_s_setprio(1);
#pragma unroll
        for (int nt = 0; nt < 4; ++nt)
#pragma unroll
          for (int ct = 0; ct < 2; ++ct)
            accv[nt][ct] = __builtin_amdgcn_mfma_f32_16x16x32_bf16(ax[nt], bw[ct], accv[nt][ct], 0, 0, 0);
        __builtin_amdgcn_s_setprio(0);
      }
#pragma unroll
      for (int nt = 0; nt < 4; ++nt)
#pragma unroll
        for (int ct = 0; ct < 2; ++ct) vfr[nt][ct] = pk4(accv[nt][ct]);
    }

    { // ---- Q^T = (SCALE*log2e*Wq)^T X^T : tiles [at][mt] -> qfr ----
      f32x4 accq[2][4];
#pragma unroll
      for (int i = 0; i < 2; ++i)
#pragma unroll
        for (int j = 0; j < 4; ++j) accq[i][j] = z4;
#pragma unroll
      for (int kk = 0; kk < 4; ++kk) {
        bf16x8 aw[2], bx[4];
#pragma unroll
        for (int at = 0; at < 2; ++at)
          aw[at] = *(const bf16x8*)(wsq + (hc + at * 16 + lo) * DIM + kk * 32 + g * 8);
#pragma unroll
        for (int mt = 0; mt < 4; ++mt)
          bx[mt] = *(const bf16x8*)&Xb[XSWZ(mt * 16 + lo, kk * 32 + g * 8)];
        __builtin_amdgcn_s_setprio(1);
#pragma unroll
        for (int at = 0; at < 2; ++at)
#pragma unroll
          for (int mt = 0; mt < 4; ++mt)
            accq[at][mt] = __builtin_amdgcn_mfma_f32_16x16x32_bf16(aw[at], bx[mt], accq[at][mt], 0, 0, 0);
        __builtin_amdgcn_s_setprio(0);
      }
#pragma unroll
      for (int at = 0; at < 2; ++at)
#pragma unroll
        for (int mt = 0; mt < 4; ++mt) qfr[at][mt] = pk4(accq[at][mt]);
    }

    // ---- per mt: S^T (K=16 x8) -> exp2 -> pk4 -> {res kk-loop || PV} -> store ----
#pragma unroll
    for (int mt = 0; mt < 4; ++mt) {
      f32x4 sv[4];
      __builtin_amdgcn_s_setprio(1);
#pragma unroll
      for (int nt = 0; nt < 4; ++nt)
        sv[nt] = MFMA16(kfr[0][nt], qfr[0][mt], z4);
#pragma unroll
      for (int nt = 0; nt < 4; ++nt)
        sv[nt] = MFMA16(kfr[1][nt], qfr[1][mt], sv[nt]);
      __builtin_amdgcn_s_setprio(0);
      // E = 2^S (scores pre-scaled by log2e); no max-subtract (range-safe)
      float ps[4];
#pragma unroll
      for (int nt = 0; nt < 4; ++nt) {
        float e0 = __builtin_amdgcn_exp2f(sv[nt][0]);
        float e1 = __builtin_amdgcn_exp2f(sv[nt][1]);
        float e2 = __builtin_amdgcn_exp2f(sv[nt][2]);
        float e3 = __builtin_amdgcn_exp2f(sv[nt][3]);
        sv[nt][0] = e0; sv[nt][1] = e1; sv[nt][2] = e2; sv[nt][3] = e3;
        ps[nt] = (e0 + e1) + (e2 + e3);  // tree partial
      }
      float sum = (ps[0] + ps[1]) + (ps[2] + ps[3]);
      s16x4 pfr[4];
#pragma unroll
      for (int nt = 0; nt < 4; ++nt) pfr[nt] = pk4(sv[nt]);
      // res^T strip for THIS mt (all 4 kk): independent stream, fills stalls
      f32x4 ch[2] = {z4, z4};
#pragma unroll
      for (int kk = 0; kk < 4; ++kk) {
        bf16x8 bxr = *(const bf16x8*)&Xb[XSWZ(mt * 16 + lo, kk * 32 + g * 8)];
        bf16x8 awr0 = *(const bf16x8*)(wsr + (hc + lo) * DIM + kk * 32 + g * 8);
        bf16x8 awr1 = *(const bf16x8*)(wsr + (hc + 16 + lo) * DIM + kk * 32 + g * 8);
        __builtin_amdgcn_s_setprio(1);
        ch[0] = __builtin_amdgcn_mfma_f32_16x16x32_bf16(awr0, bxr, ch[0], 0, 0, 0);
        ch[1] = __builtin_amdgcn_mfma_f32_16x16x32_bf16(awr1, bxr, ch[1], 0, 0, 0);
        __builtin_amdgcn_s_setprio(0);
      }
      // sum reduce off the P path
      sum += __shfl_xor(sum, 16, 64);
      sum += __shfl_xor(sum, 32, 64);
      float rinv = __builtin_amdgcn_rcpf(sum);
      // PV: ctx^T[c][m] = sum_n V^T[c][n] P^T[n][m], all in registers
      __builtin_amdgcn_s_setprio(1);
#pragma unroll
      for (int ct = 0; ct < 2; ++ct) {
        f32x4 a = MFMA16(vfr[0][ct], pfr[0], z4);
        a = MFMA16(vfr[1][ct], pfr[1], a);
        a = MFMA16(vfr[2][ct], pfr[2], a);
        a = MFMA16(vfr[3][ct], pfr[3], a);
#pragma unroll
        for (int j = 0; j < 4; ++j)
          ch[ct][j] = fmaf(a[j], rinv, ch[ct][j]);  // ctx/sum into res acc
      }
      __builtin_amdgcn_s_setprio(0);
      // ReLU + float4 store: rows c = hc+ct*16+4g+j, col m = mt*16+lo
#pragma unroll
      for (int ct = 0; ct < 2; ++ct) {
        float4 o;
        o.x = fmaxf(ch[ct][0], 0.f);
        o.y = fmaxf(ch[ct][1], 0.f);
        o.z = fmaxf(ch[ct][2], 0.f);
        o.w = fmaxf(ch[ct][3], 0.f);
        *(float4*)(ob + (mt * 16 + lo) * HKC + hc + ct * 16 + 4 * g) = o;
      }
    }
  }
}

extern "C" void kernel_launch(void* const* d_in, const int* in_sizes, int n_in,
                              void* d_out, int out_size, void* d_ws, size_t ws_size,
                              hipStream_t stream) {
  const float* x  = (const float*)d_in[0];
  const float* Wq = (const float*)d_in[1];
  const float* Wk = (const float*)d_in[2];
  const float* Wv = (const float*)d_in[3];
  const float* Wr = (const float*)d_in[4];
  bf16_t* ws = (bf16_t*)d_ws;
  float* out = (float*)d_out;

  prep_weights<<<512, 256, 0, stream>>>(Wq, Wk, Wv, Wr, ws);
  fused_attn<<<NB, 256, 0, stream>>>(x, ws, out);
}

// Round 19
// 178.183 us; speedup vs baseline: 1.3894x; 1.3894x over previous
//
#include <hip/hip_runtime.h>

#define NB    4096
#define SEQ   64
#define DIM   128
#define NHEAD 8
#define ATTD  32
#define HKC   256
#define SCALE 0.17677669529663687f
#define LOG2E 1.4426950408889634f

typedef __bf16 bf16_t;
typedef __bf16 bf16x8 __attribute__((ext_vector_type(8)));
typedef __bf16 bf16x4 __attribute__((ext_vector_type(4)));
typedef float  f32x4  __attribute__((ext_vector_type(4)));
typedef short  s16x4  __attribute__((ext_vector_type(4)));
typedef unsigned int u32;

// K=16 MFMA: A/B frag layout (row/col=lane&15, k=4*(lane>>4)+elem) == the
// D-layout of a 16x16 MFMA (col=lane&15, row=4*(lane>>4)+reg). Any 16x16
// D-tile feeds the next MFMA's K-dim directly after an in-lane f32->bf16 pack.
#define MFMA16(a, b, c) __builtin_amdgcn_mfma_f32_16x16x16bf16_1k(a, b, c, 0, 0, 0)

// native casts -> v_cvt_pk_bf16_f32 (RNE)
static __device__ __forceinline__ u32 pkbf(float a, float b) {
  unsigned short ua = __builtin_bit_cast(unsigned short, (__bf16)a);
  unsigned short ub = __builtin_bit_cast(unsigned short, (__bf16)b);
  return (u32)ua | ((u32)ub << 16);
}

// pack a 16x16 D-tile (4 f32 regs) into a K=16 A/B frag (4 bf16 = 2 regs),
// pure in-lane: elem e = reg j. No shuffles, no LDS.
static __device__ __forceinline__ s16x4 pk4(f32x4 t) {
  union { u32 u[2]; s16x4 s; } r;
  r.u[0] = pkbf(t[0], t[1]);
  r.u[1] = pkbf(t[2], t[3]);
  return r.s;
}

// XOR swizzle on element index (XOR bits >=3 only: 16B blocks stay contiguous)
#define XSWZ(r, c) (((r) << 7) + ((c) ^ (((r) & 7) << 3)))   // Xb: 64x128

// ws layout (bf16): [0:32768) WqT[c][d] (pre-scaled by SCALE*log2e),
// [32768:65536) WkT, [65536:98304) WvT, [98304:131072) WresT.
__global__ void prep_weights(const float* __restrict__ Wq,
                             const float* __restrict__ Wk,
                             const float* __restrict__ Wv,
                             const float* __restrict__ Wr,
                             bf16_t* __restrict__ ws) {
  int idx = blockIdx.x * 256 + threadIdx.x;  // 0..131071
  int m = idx >> 15;
  int e = idx & 32767;
  int c = e >> 7;
  int d = e & 127;
  float v;
  if (m == 0)      v = Wq[((c >> 5) * DIM + d) * ATTD + (c & 31)] * (SCALE * LOG2E);
  else if (m == 1) v = Wk[((c >> 5) * DIM + d) * ATTD + (c & 31)];
  else if (m == 2) v = Wv[((c >> 5) * DIM + d) * ATTD + (c & 31)];
  else             v = Wr[d * HKC + c];
  ws[idx] = (bf16_t)v;
}

// FINAL (R17, best measured 178.5 us): R12 op-structure with the attention
// stage on K=16 MFMAs — proj D-tiles feed S/PV frags directly via in-lane
// pk4 (merge2, Vt LDS, Pt LDS all deleted). Per-mt chain is register-only:
// S-MFMA -> exp2 -> pk4 -> PV. Res MFMAs (K=32) interleaved per-mt to fill
// softmax stalls. Operating point: 3 waves/SIMD, ~84 arch VGPR (proven over
// R4/R5/R9/R10/R15/R18: any 4-wave budget spills or collapses ILP).
__launch_bounds__(256, 3)
__global__ void fused_attn(const float* __restrict__ xg,
                           const bf16_t* __restrict__ ws,
                           float* __restrict__ outg) {
  __shared__ bf16_t Xb[64 * 128];   // only LDS left (16 KB)

  const int t  = threadIdx.x;
  const int w  = t >> 6;
  const int l  = t & 63;
  const int lo = l & 15;
  const int g  = l >> 4;
  const int b  = blockIdx.x;

  { // stage X -> LDS (bf16, swizzled)
    const float* xb = xg + (size_t)b * (SEQ * DIM);
#pragma unroll
    for (int i = 0; i < 8; ++i) {
      int idx = i * 1024 + t * 4;
      float4 v = *(const float4*)(xb + idx);
      bf16x4 p;
      p[0] = (bf16_t)v.x; p[1] = (bf16_t)v.y; p[2] = (bf16_t)v.z; p[3] = (bf16_t)v.w;
      *(bf16x4*)&Xb[XSWZ(idx >> 7, idx & 127)] = p;
    }
  }
  __syncthreads();

  const bf16_t* wsq = ws;
  const bf16_t* wsk = ws + 32768;
  const bf16_t* wsv = ws + 65536;
  const bf16_t* wsr = ws + 98304;
  float* ob = outg + (size_t)b * (SEQ * HKC);
  const f32x4 z4 = {0.f, 0.f, 0.f, 0.f};

#pragma unroll
  for (int hh = 0; hh < 2; ++hh) {
    const int hc = w * 64 + hh * 32;  // weight col base == output col base

    s16x4 kfr[2][4], vfr[4][2], qfr[2][4];

    { // ---- K^T = Wk^T X^T : tiles [at][nt] (rows a, cols n) -> kfr ----
      f32x4 acck[2][4];
#pragma unroll
      for (int i = 0; i < 2; ++i)
#pragma unroll
        for (int j = 0; j < 4; ++j) acck[i][j] = z4;
#pragma unroll
      for (int kk = 0; kk < 4; ++kk) {
        bf16x8 aw[2], bx[4];
#pragma unroll
        for (int at = 0; at < 2; ++at)
          aw[at] = *(const bf16x8*)(wsk + (hc + at * 16 + lo) * DIM + kk * 32 + g * 8);
#pragma unroll
        for (int nt = 0; nt < 4; ++nt)
          bx[nt] = *(const bf16x8*)&Xb[XSWZ(nt * 16 + lo, kk * 32 + g * 8)];
        __builtin_amdgcn_s_setprio(1);
#pragma unroll
        for (int at = 0; at < 2; ++at)
#pragma unroll
          for (int nt = 0; nt < 4; ++nt)
            acck[at][nt] = __builtin_amdgcn_mfma_f32_16x16x32_bf16(aw[at], bx[nt], acck[at][nt], 0, 0, 0);
        __builtin_amdgcn_s_setprio(0);
      }
      // D(row a=4g+j, col n=lo) -> S A-frag(row n=lo, k a=4g+e): in-lane pack
#pragma unroll
      for (int at = 0; at < 2; ++at)
#pragma unroll
        for (int nt = 0; nt < 4; ++nt) kfr[at][nt] = pk4(acck[at][nt]);
    }

    { // ---- V = X Wv : tiles [nt][ct] (rows n, cols c) -> vfr ----
      f32x4 accv[4][2];
#pragma unroll
      for (int i = 0; i < 4; ++i)
#pragma unroll
        for (int j = 0; j < 2; ++j) accv[i][j] = z4;
#pragma unroll
      for (int kk = 0; kk < 4; ++kk) {
        bf16x8 ax[4], bw[2];
#pragma unroll
        for (int nt = 0; nt < 4; ++nt)
          ax[nt] = *(const bf16x8*)&Xb[XSWZ(nt * 16 + lo, kk * 32 + g * 8)];
#pragma unroll
        for (int ct = 0; ct < 2; ++ct)
          bw[ct] = *(const bf16x8*)(wsv + (hc + ct * 16 + lo) * DIM + kk * 32 + g * 8);
        __builtin_amdgcn_s_setprio(1);
#pragma unroll
        for (int nt = 0; nt < 4; ++nt)
#pragma unroll
          for (int ct = 0; ct < 2; ++ct)
            accv[nt][ct] = __builtin_amdgcn_mfma_f32_16x16x32_bf16(ax[nt], bw[ct], accv[nt][ct], 0, 0, 0);
        __builtin_amdgcn_s_setprio(0);
      }
      // D(row n=4g+j, col c=lo) -> PV A-frag(row c=lo, k n=4g+e): in-lane pack
#pragma unroll
      for (int nt = 0; nt < 4; ++nt)
#pragma unroll
        for (int ct = 0; ct < 2; ++ct) vfr[nt][ct] = pk4(accv[nt][ct]);
    }

    { // ---- Q^T = (SCALE*log2e*Wq)^T X^T : tiles [at][mt] -> qfr ----
      f32x4 accq[2][4];
#pragma unroll
      for (int i = 0; i < 2; ++i)
#pragma unroll
        for (int j = 0; j < 4; ++j) accq[i][j] = z4;
#pragma unroll
      for (int kk = 0; kk < 4; ++kk) {
        bf16x8 aw[2], bx[4];
#pragma unroll
        for (int at = 0; at < 2; ++at)
          aw[at] = *(const bf16x8*)(wsq + (hc + at * 16 + lo) * DIM + kk * 32 + g * 8);
#pragma unroll
        for (int mt = 0; mt < 4; ++mt)
          bx[mt] = *(const bf16x8*)&Xb[XSWZ(mt * 16 + lo, kk * 32 + g * 8)];
        __builtin_amdgcn_s_setprio(1);
#pragma unroll
        for (int at = 0; at < 2; ++at)
#pragma unroll
          for (int mt = 0; mt < 4; ++mt)
            accq[at][mt] = __builtin_amdgcn_mfma_f32_16x16x32_bf16(aw[at], bx[mt], accq[at][mt], 0, 0, 0);
        __builtin_amdgcn_s_setprio(0);
      }
      // D(row a=4g+j, col m=lo) -> S B-frag(k a=4g+e, col m=lo): in-lane pack
#pragma unroll
      for (int at = 0; at < 2; ++at)
#pragma unroll
        for (int mt = 0; mt < 4; ++mt) qfr[at][mt] = pk4(accq[at][mt]);
    }

    // ---- per mt: {S^T (K=16 x2), exp2, pk4 -> PV (K=16 x4)} || {res kk=mt} ----
    f32x4 ch[2][4];  // [ct][mt]: rows c = 4g+j, cols m = lo; res + ctx/sum
#pragma unroll
    for (int i = 0; i < 2; ++i)
#pragma unroll
      for (int j = 0; j < 4; ++j) ch[i][j] = z4;
#pragma unroll
    for (int mt = 0; mt < 4; ++mt) {
      f32x4 sv[4];
      __builtin_amdgcn_s_setprio(1);
#pragma unroll
      for (int nt = 0; nt < 4; ++nt)
        sv[nt] = MFMA16(kfr[0][nt], qfr[0][mt], z4);
#pragma unroll
      for (int nt = 0; nt < 4; ++nt)
        sv[nt] = MFMA16(kfr[1][nt], qfr[1][mt], sv[nt]);
      __builtin_amdgcn_s_setprio(0);
      // independent res stream for kk = mt (loads issue under the softmax chain)
      bf16x8 bxr[4], awr[2];
#pragma unroll
      for (int mtj = 0; mtj < 4; ++mtj)
        bxr[mtj] = *(const bf16x8*)&Xb[XSWZ(mtj * 16 + lo, mt * 32 + g * 8)];
#pragma unroll
      for (int ct = 0; ct < 2; ++ct)
        awr[ct] = *(const bf16x8*)(wsr + (hc + ct * 16 + lo) * DIM + mt * 32 + g * 8);
      // E = 2^S (scores pre-scaled by log2e); no max-subtract (range-safe)
      float ps[4];
#pragma unroll
      for (int nt = 0; nt < 4; ++nt) {
        float e0 = __builtin_amdgcn_exp2f(sv[nt][0]);
        float e1 = __builtin_amdgcn_exp2f(sv[nt][1]);
        float e2 = __builtin_amdgcn_exp2f(sv[nt][2]);
        float e3 = __builtin_amdgcn_exp2f(sv[nt][3]);
        sv[nt][0] = e0; sv[nt][1] = e1; sv[nt][2] = e2; sv[nt][3] = e3;
        ps[nt] = (e0 + e1) + (e2 + e3);  // tree partial
      }
      float sum = (ps[0] + ps[1]) + (ps[2] + ps[3]);
      // P^T D(row n=4g+j, col m=lo) -> PV B-frag(k n=4g+e, col m=lo): in-lane
      s16x4 pfr[4];
#pragma unroll
      for (int nt = 0; nt < 4; ++nt) pfr[nt] = pk4(sv[nt]);
      // res MFMAs: independent of the softmax chain, fill its stalls
      __builtin_amdgcn_s_setprio(1);
#pragma unroll
      for (int ct = 0; ct < 2; ++ct)
#pragma unroll
        for (int mtj = 0; mtj < 4; ++mtj)
          ch[ct][mtj] = __builtin_amdgcn_mfma_f32_16x16x32_bf16(awr[ct], bxr[mtj], ch[ct][mtj], 0, 0, 0);
      __builtin_amdgcn_s_setprio(0);
      // sum reduce off the P path
      sum += __shfl_xor(sum, 16, 64);
      sum += __shfl_xor(sum, 32, 64);
      float rinv = __builtin_amdgcn_rcpf(sum);
      // PV: ctx^T[c][m] = sum_n V^T[c][n] P^T[n][m], all in registers
      __builtin_amdgcn_s_setprio(1);
#pragma unroll
      for (int ct = 0; ct < 2; ++ct) {
        f32x4 a = MFMA16(vfr[0][ct], pfr[0], z4);
        a = MFMA16(vfr[1][ct], pfr[1], a);
        a = MFMA16(vfr[2][ct], pfr[2], a);
        a = MFMA16(vfr[3][ct], pfr[3], a);
#pragma unroll
        for (int j = 0; j < 4; ++j)
          ch[ct][mt][j] = fmaf(a[j], rinv, ch[ct][mt][j]);  // ctx/sum into res acc
      }
      __builtin_amdgcn_s_setprio(0);
    }

    // ---- ReLU + float4 store: rows c = hc+ct*16+4g+j, col m = mt*16+lo ----
#pragma unroll
    for (int ct = 0; ct < 2; ++ct)
#pragma unroll
      for (int mt = 0; mt < 4; ++mt) {
        float4 o;
        o.x = fmaxf(ch[ct][mt][0], 0.f);
        o.y = fmaxf(ch[ct][mt][1], 0.f);
        o.z = fmaxf(ch[ct][mt][2], 0.f);
        o.w = fmaxf(ch[ct][mt][3], 0.f);
        *(float4*)(ob + (mt * 16 + lo) * HKC + hc + ct * 16 + 4 * g) = o;
      }
  }
}

extern "C" void kernel_launch(void* const* d_in, const int* in_sizes, int n_in,
                              void* d_out, int out_size, void* d_ws, size_t ws_size,
                              hipStream_t stream) {
  const float* x  = (const float*)d_in[0];
  const float* Wq = (const float*)d_in[1];
  const float* Wk = (const float*)d_in[2];
  const float* Wv = (const float*)d_in[3];
  const float* Wr = (const float*)d_in[4];
  bf16_t* ws = (bf16_t*)d_ws;
  float* out = (float*)d_out;

  prep_weights<<<512, 256, 0, stream>>>(Wq, Wk, Wv, Wr, ws);
  fused_attn<<<NB, 256, 0, stream>>>(x, ws, out);
}